// Round 1
// baseline (6821.590 us; speedup 1.0000x reference)
//
#include <hip/hip_runtime.h>
#include <math.h>
#include <complex>

#define NN 100000
#define NE 1600000
#define NG 64

// ---------------- CG tables (computed on host, passed by value) ----------------
struct CGTables {
  float c000;          // (0,0,0)
  float c011[3][3];    // [o][b]  W[o][0][b]
  float c101[3][3];    // [o][a]  W[o][a][0]
  float c110[3][3];    // [a][b]  W[0][a][b]
  float c111[3][3][3]; // [o][a][b]
  float c121[3][3][5]; // [o][a][b]
};

static double hfact(int n){ double r=1.0; for(int i=2;i<=n;++i) r*=(double)i; return r; }

static double host_cgc(int j1,int m1,int j2,int m2,int j3,int m3){
  if (m1+m2 != m3) return 0.0;
  double pre = sqrt((2.0*j3+1.0)*hfact(j3+j1-j2)*hfact(j3-j1+j2)*hfact(j1+j2-j3)/hfact(j1+j2+j3+1));
  pre *= sqrt(hfact(j3+m3)*hfact(j3-m3)*hfact(j1-m1)*hfact(j1+m1)*hfact(j2-m2)*hfact(j2+m2));
  int k0 = 0; if (j2-j3-m1 > k0) k0 = j2-j3-m1; if (j1-j3+m2 > k0) k0 = j1-j3+m2;
  int k1 = j1+j2-j3; if (j1-m1 < k1) k1 = j1-m1; if (j2+m2 < k1) k1 = j2+m2;
  double s = 0.0;
  for (int k=k0;k<=k1;++k){
    double t = 1.0/(hfact(k)*hfact(j1+j2-j3-k)*hfact(j1-m1-k)*hfact(j2+m2-k)*hfact(j3-j2+m1+k)*hfact(j3-j1-m2+k));
    s += (k&1) ? -t : t;
  }
  return pre*s;
}

typedef std::complex<double> cd;

static void host_u(int l, cd U[5][5]){
  for (int a=0;a<5;++a) for (int b=0;b<5;++b) U[a][b] = 0.0;
  U[l][l] = 1.0;
  const double is2 = 1.0/sqrt(2.0);
  for (int m=1;m<=l;++m){
    double sgn = (m&1) ? -1.0 : 1.0;
    U[l+m][l+m] = sgn*is2;
    U[l+m][l-m] = is2;
    U[l-m][l-m] = cd(0.0, is2);
    U[l-m][l+m] = cd(0.0, -sgn*is2);
  }
}

static void host_real_cg(int l1,int l2,int l3, float* out /* [n3][n1][n2] row-major */){
  cd U1[5][5], U2[5][5], U3[5][5];
  host_u(l1,U1); host_u(l2,U2); host_u(l3,U3);
  int n1=2*l1+1, n2=2*l2+1, n3=2*l3+1;
  double cgt[5][5][5];
  for (int i=0;i<5;++i) for (int j=0;j<5;++j) for (int k=0;k<5;++k) cgt[i][j][k]=0.0;
  for (int m1=-l1;m1<=l1;++m1) for (int m2=-l2;m2<=l2;++m2){
    int m3 = m1+m2;
    if (m3 >= -l3 && m3 <= l3) cgt[l1+m1][l2+m2][l3+m3] = host_cgc(l1,m1,l2,m2,l3,m3);
  }
  cd W[5][5][5];
  double sre=0.0, sim=0.0;
  for (int c=0;c<n3;++c) for (int a=0;a<n1;++a) for (int b=0;b<n2;++b){
    cd acc = 0.0;
    for (int i=0;i<n1;++i) for (int j=0;j<n2;++j) for (int k=0;k<n3;++k)
      acc += U1[a][i]*U2[b][j]*std::conj(U3[c][k])*cgt[i][j][k];
    W[c][a][b] = acc;
    sre += fabs(acc.real()); sim += fabs(acc.imag());
  }
  bool use_re = (sre >= sim);
  for (int c=0;c<n3;++c) for (int a=0;a<n1;++a) for (int b=0;b<n2;++b)
    out[(c*n1+a)*n2+b] = (float)(use_re ? W[c][a][b].real() : W[c][a][b].imag());
}

static void build_cg_tables(CGTables& t){
  float w000[1];  host_real_cg(0,0,0,w000); t.c000 = w000[0];
  float w011[9];  host_real_cg(0,1,1,w011);
  for (int o=0;o<3;++o) for (int b=0;b<3;++b) t.c011[o][b] = w011[o*3+b];
  float w101[9];  host_real_cg(1,0,1,w101);
  for (int o=0;o<3;++o) for (int a=0;a<3;++a) t.c101[o][a] = w101[o*3+a];
  float w110[9];  host_real_cg(1,1,0,w110);
  for (int a=0;a<3;++a) for (int b=0;b<3;++b) t.c110[a][b] = w110[a*3+b];
  float w111[27]; host_real_cg(1,1,1,w111);
  for (int o=0;o<3;++o) for (int a=0;a<3;++a) for (int b=0;b<3;++b) t.c111[o][a][b] = w111[(o*3+a)*3+b];
  float w121[45]; host_real_cg(1,2,1,w121);
  for (int o=0;o<3;++o) for (int a=0;a<3;++a) for (int b=0;b<5;++b) t.c121[o][a][b] = w121[(o*3+a)*5+b];
}

// ---------------- device helpers ----------------
__device__ __forceinline__ float sspf(float v){
  float sp = (v > 30.0f) ? v : log1pf(expf(v));
  return sp - 0.69314718055994531f;
}

__device__ __forceinline__ float cutoff_w(float len){
  float u = len * (1.0f/1.5f);
  float u2 = u*u, u6 = u2*u2*u2, u7 = u6*u, u8 = u7*u;
  float cut = 1.0f - 28.0f*u6 + 48.0f*u7 - 21.0f*u8;
  return (u < 1.0f) ? cut : 0.0f;
}

// ---------------- edge kernel, block 1 (c_in=1, paths (000),(011), not channel-wise) ----------------
__global__ __launch_bounds__(256) void edge1_kernel(
    const float* __restrict__ x, const int* __restrict__ src, const int* __restrict__ dst,
    const float* __restrict__ sh, const float* __restrict__ elen,
    const float* __restrict__ wpw, const float* __restrict__ wpb,
    float* __restrict__ agg, CGTables cg)
{
  __shared__ float sw[176];
  for (int i=threadIdx.x;i<176;i+=256) sw[i] = (i<160) ? wpw[i] : wpb[i-160];
  __syncthreads();
  int e = blockIdx.x*256 + threadIdx.x;
  if (e >= NE) return;
  float len = elen[e];
  float lw[16];
  #pragma unroll
  for (int j=0;j<16;++j) lw[j] = sw[160+j];
  #pragma unroll
  for (int i=0;i<10;++i){
    float dd = len - (0.7f + (float)i*(1.0f/9.0f));
    float em = expf(-50.0f*dd*dd);
    #pragma unroll
    for (int j=0;j<16;++j) lw[j] += em*sw[i*16+j];
  }
  float w = cutoff_w(len);
  int s = src[e], d = dst[e];
  float x0 = x[s];
  const float* shr = sh + (size_t)e*9;
  float sh0 = shr[0], sh1 = shr[1], sh2 = shr[2], sh3 = shr[3];
  float s011[3];
  #pragma unroll
  for (int o=0;o<3;++o) s011[o] = cg.c011[o][0]*sh1 + cg.c011[o][1]*sh2 + cg.c011[o][2]*sh3;
  float* ag = agg + (size_t)d*32;
  float b0 = cg.c000*x0*sh0*w;
  #pragma unroll
  for (int j=0;j<8;++j) unsafeAtomicAdd(ag+j, b0*lw[j]);
  #pragma unroll
  for (int o=0;o<3;++o){
    float bo = s011[o]*x0*w;
    #pragma unroll
    for (int j=0;j<8;++j) unsafeAtomicAdd(ag+(1+o)*8+j, bo*lw[8+j]);
  }
}

// ---------------- edge kernel, block 2 (c_in=8, 6 paths, channel-wise) ----------------
__global__ __launch_bounds__(256) void edge2_kernel(
    const float* __restrict__ h, const int* __restrict__ src, const int* __restrict__ dst,
    const float* __restrict__ sh, const float* __restrict__ elen,
    const float* __restrict__ wpw, const float* __restrict__ wpb,
    float* __restrict__ agg, CGTables cg)
{
  __shared__ float sw[528];
  for (int i=threadIdx.x;i<528;i+=256) sw[i] = (i<480) ? wpw[i] : wpb[i-480];
  __syncthreads();
  int e = blockIdx.x*256 + threadIdx.x;
  if (e >= NE) return;
  float len = elen[e];
  float lw[48];
  #pragma unroll
  for (int j=0;j<48;++j) lw[j] = sw[480+j];
  #pragma unroll
  for (int i=0;i<10;++i){
    float dd = len - (0.7f + (float)i*(1.0f/9.0f));
    float em = expf(-50.0f*dd*dd);
    #pragma unroll
    for (int j=0;j<48;++j) lw[j] += em*sw[i*48+j];
  }
  float w = cutoff_w(len);
  int s = src[e], d = dst[e];
  float shv[9];
  const float* shr = sh + (size_t)e*9;
  #pragma unroll
  for (int i=0;i<9;++i) shv[i] = shr[i];
  float sh0 = shv[0];
  float s011[3], k110[3], k111[3][3], k121[3][3];
  #pragma unroll
  for (int o=0;o<3;++o) s011[o] = cg.c011[o][0]*shv[1] + cg.c011[o][1]*shv[2] + cg.c011[o][2]*shv[3];
  #pragma unroll
  for (int a=0;a<3;++a) k110[a] = cg.c110[a][0]*shv[1] + cg.c110[a][1]*shv[2] + cg.c110[a][2]*shv[3];
  #pragma unroll
  for (int o=0;o<3;++o)
    #pragma unroll
    for (int a=0;a<3;++a)
      k111[o][a] = cg.c111[o][a][0]*shv[1] + cg.c111[o][a][1]*shv[2] + cg.c111[o][a][2]*shv[3];
  #pragma unroll
  for (int o=0;o<3;++o)
    #pragma unroll
    for (int a=0;a<3;++a){
      float acc = 0.0f;
      #pragma unroll
      for (int b=0;b<5;++b) acc += cg.c121[o][a][b]*shv[4+b];
      k121[o][a] = acc;
    }
  const float4* hr = reinterpret_cast<const float4*>(h + (size_t)s*32);
  float xs[32];
  #pragma unroll
  for (int i=0;i<8;++i){
    float4 q = hr[i];
    xs[i*4] = q.x; xs[i*4+1] = q.y; xs[i*4+2] = q.z; xs[i*4+3] = q.w;
  }
  float* ag = agg + (size_t)d*32;
  #pragma unroll
  for (int c=0;c<8;++c){
    float x0 = xs[c], x1 = xs[8+c], x2 = xs[16+c], x3 = xs[24+c];
    float r0 = cg.c000*sh0*x0*lw[c]
             + (k110[0]*x1 + k110[1]*x2 + k110[2]*x3)*lw[24+c];
    unsafeAtomicAdd(ag+c, r0*w);
    #pragma unroll
    for (int o=0;o<3;++o){
      float r = s011[o]*x0*lw[8+c]
              + (cg.c101[o][0]*x1 + cg.c101[o][1]*x2 + cg.c101[o][2]*x3)*sh0*lw[16+c]
              + (k111[o][0]*x1 + k111[o][1]*x2 + k111[o][2]*x3)*lw[32+c]
              + (k121[o][0]*x1 + k121[o][1]*x2 + k121[o][2]*x3)*lw[40+c];
      unsafeAtomicAdd(ag+(1+o)*8+c, r*w);
    }
  }
}

// ---------------- edge kernel, block 3 (paths (000),(110), out l=0 only) ----------------
__global__ __launch_bounds__(256) void edge3_kernel(
    const float* __restrict__ h, const int* __restrict__ src, const int* __restrict__ dst,
    const float* __restrict__ sh, const float* __restrict__ elen,
    const float* __restrict__ wpw, const float* __restrict__ wpb,
    float* __restrict__ agg, CGTables cg)
{
  __shared__ float sw[176];
  for (int i=threadIdx.x;i<176;i+=256) sw[i] = (i<160) ? wpw[i] : wpb[i-160];
  __syncthreads();
  int e = blockIdx.x*256 + threadIdx.x;
  if (e >= NE) return;
  float len = elen[e];
  float lw[16];
  #pragma unroll
  for (int j=0;j<16;++j) lw[j] = sw[160+j];
  #pragma unroll
  for (int i=0;i<10;++i){
    float dd = len - (0.7f + (float)i*(1.0f/9.0f));
    float em = expf(-50.0f*dd*dd);
    #pragma unroll
    for (int j=0;j<16;++j) lw[j] += em*sw[i*16+j];
  }
  float w = cutoff_w(len);
  int s = src[e], d = dst[e];
  const float* shr = sh + (size_t)e*9;
  float sh0 = shr[0], sh1 = shr[1], sh2 = shr[2], sh3 = shr[3];
  float k110[3];
  #pragma unroll
  for (int a=0;a<3;++a) k110[a] = cg.c110[a][0]*sh1 + cg.c110[a][1]*sh2 + cg.c110[a][2]*sh3;
  const float4* hr = reinterpret_cast<const float4*>(h + (size_t)s*32);
  float xs[32];
  #pragma unroll
  for (int i=0;i<8;++i){
    float4 q = hr[i];
    xs[i*4] = q.x; xs[i*4+1] = q.y; xs[i*4+2] = q.z; xs[i*4+3] = q.w;
  }
  float* ag = agg + (size_t)d*8;
  #pragma unroll
  for (int c=0;c<8;++c){
    float r = cg.c000*sh0*xs[c]*lw[c]
            + (k110[0]*xs[8+c] + k110[1]*xs[16+c] + k110[2]*xs[24+c])*lw[8+c];
    unsafeAtomicAdd(ag+c, r*w);
  }
}

// ---------------- node kernel (self-interaction 8x8 + norm-act), blocks 1&2 ----------------
__global__ __launch_bounds__(256) void node_kernel(
    const float* __restrict__ agg, const float* __restrict__ si /* (2,8,8) */,
    float* __restrict__ out)
{
  __shared__ float s_si[128];
  if (threadIdx.x < 128) s_si[threadIdx.x] = si[threadIdx.x];
  __syncthreads();
  int idx = blockIdx.x*256 + threadIdx.x;
  if (idx >= NN*8) return;
  int n = idx >> 3, d = idx & 7;
  const float* ar = agg + (size_t)n*32;
  float y[4];
  #pragma unroll
  for (int m=0;m<4;++m){
    const float* sm = s_si + (m ? 64 : 0);
    float acc = 0.0f;
    #pragma unroll
    for (int c=0;c<8;++c) acc += ar[m*8+c]*sm[c*8+d];
    y[m] = acc;
  }
  float n0 = sqrtf(y[0]*y[0] + 1e-12f);
  float r0 = y[0]*(sspf(n0)/n0);
  float n1 = sqrtf(y[1]*y[1] + y[2]*y[2] + y[3]*y[3] + 1e-12f);
  float sc = sspf(n1)/n1;
  float* orow = out + (size_t)n*32;
  orow[d]      = r0;
  orow[8+d]    = y[1]*sc;
  orow[16+d]   = y[2]*sc;
  orow[24+d]   = y[3]*sc;
}

// ---------------- node kernel 3: self-interaction + silu + graph pool ----------------
__global__ __launch_bounds__(256) void node3_pool_kernel(
    const float* __restrict__ agg /* (N,8) */, const float* __restrict__ si /* (1,8,8) */,
    const int* __restrict__ batch, float* __restrict__ g /* (64,8) */)
{
  __shared__ float s_si[64];
  if (threadIdx.x < 64) s_si[threadIdx.x] = si[threadIdx.x];
  __syncthreads();
  int n = blockIdx.x*256 + threadIdx.x;
  if (n >= NN) return;
  const float* ar = agg + (size_t)n*8;
  float av[8];
  #pragma unroll
  for (int c=0;c<8;++c) av[c] = ar[c];
  int b = batch[n];
  float* gr = g + (size_t)b*8;
  #pragma unroll
  for (int d=0;d<8;++d){
    float acc = 0.0f;
    #pragma unroll
    for (int c=0;c<8;++c) acc += av[c]*s_si[c*8+d];
    float v = acc / (1.0f + expf(-acc));   // silu
    unsafeAtomicAdd(gr+d, v);
  }
}

// ---------------- final: logits + softmax ----------------
__global__ void final_kernel(
    const float* __restrict__ g, const float* __restrict__ ow /* (8,8) */,
    const float* __restrict__ ob, float* __restrict__ out)
{
  int i = threadIdx.x;
  if (i >= NG) return;
  float gv[8];
  #pragma unroll
  for (int c=0;c<8;++c) gv[c] = g[i*8+c];
  float lg[8];
  #pragma unroll
  for (int j=0;j<8;++j){
    float acc = ob[j];
    #pragma unroll
    for (int c=0;c<8;++c) acc += gv[c]*ow[c*8+j];
    lg[j] = acc;
  }
  float mx = lg[0];
  #pragma unroll
  for (int j=1;j<8;++j) mx = fmaxf(mx, lg[j]);
  float ssum = 0.0f;
  #pragma unroll
  for (int j=0;j<8;++j){ lg[j] = expf(lg[j]-mx); ssum += lg[j]; }
  float inv = 1.0f/ssum;
  #pragma unroll
  for (int j=0;j<8;++j) out[i*8+j] = lg[j]*inv;
}

// ---------------- launch ----------------
extern "C" void kernel_launch(void* const* d_in, const int* in_sizes, int n_in,
                              void* d_out, int out_size, void* d_ws, size_t ws_size,
                              hipStream_t stream)
{
  const float* x     = (const float*)d_in[0];
  const int*   eidx  = (const int*)  d_in[1];
  const float* esh   = (const float*)d_in[2];
  const float* elen  = (const float*)d_in[3];
  const int*   batch = (const int*)  d_in[4];
  const float* wp1w  = (const float*)d_in[5];
  const float* wp1b  = (const float*)d_in[6];
  const float* wp2w  = (const float*)d_in[7];
  const float* wp2b  = (const float*)d_in[8];
  const float* wp3w  = (const float*)d_in[9];
  const float* wp3b  = (const float*)d_in[10];
  const float* si1   = (const float*)d_in[11];
  const float* si2   = (const float*)d_in[12];
  const float* si3   = (const float*)d_in[13];
  const float* outw  = (const float*)d_in[14];
  const float* outb  = (const float*)d_in[15];
  const int* src = eidx;
  const int* dst = eidx + NE;

  float* A = (float*)d_ws;                 // N*32  (aggregate, blocks 1&2)
  float* B = A + (size_t)NN*32;            // N*32  (activated node features)
  float* C = B + (size_t)NN*32;            // N*8   (aggregate, block 3)
  float* G = C + (size_t)NN*8;             // 64*8  (graph sums)

  CGTables cg;
  build_cg_tables(cg);

  const int EB = (NE + 255)/256;
  const int NB8 = (NN*8 + 255)/256;
  const int NB = (NN + 255)/256;

  hipMemsetAsync(A, 0, (size_t)NN*32*sizeof(float), stream);
  edge1_kernel<<<EB, 256, 0, stream>>>(x, src, dst, esh, elen, wp1w, wp1b, A, cg);
  node_kernel<<<NB8, 256, 0, stream>>>(A, si1, B);
  hipMemsetAsync(A, 0, (size_t)NN*32*sizeof(float), stream);
  edge2_kernel<<<EB, 256, 0, stream>>>(B, src, dst, esh, elen, wp2w, wp2b, A, cg);
  node_kernel<<<NB8, 256, 0, stream>>>(A, si2, B);
  hipMemsetAsync(C, 0, (size_t)NN*8*sizeof(float), stream);
  edge3_kernel<<<EB, 256, 0, stream>>>(B, src, dst, esh, elen, wp3w, wp3b, C, cg);
  hipMemsetAsync(G, 0, (size_t)NG*8*sizeof(float), stream);
  node3_pool_kernel<<<NB, 256, 0, stream>>>(C, si3, batch, G);
  final_kernel<<<1, 64, 0, stream>>>(G, outw, outb, (float*)d_out);
}

// Round 2
// 488.327 us; speedup vs baseline: 13.9693x; 13.9693x over previous
//
#include <hip/hip_runtime.h>
#include <math.h>
#include <complex>

#define NN 100000
#define NE 1600000
#define NG 64
#define NBLK_E   6250   // NE/256
#define NBLK_N8  3125   // NN*8/256
#define NBLK_SCAN 391   // ceil(NN/256)

// ---------------- CG tables (computed on host, passed by value) ----------------
struct CGTables {
  float c000;
  float c011[3][3];
  float c101[3][3];
  float c110[3][3];
  float c111[3][3][3];
  float c121[3][3][5];
};

static double hfact(int n){ double r=1.0; for(int i=2;i<=n;++i) r*=(double)i; return r; }

static double host_cgc(int j1,int m1,int j2,int m2,int j3,int m3){
  if (m1+m2 != m3) return 0.0;
  double pre = sqrt((2.0*j3+1.0)*hfact(j3+j1-j2)*hfact(j3-j1+j2)*hfact(j1+j2-j3)/hfact(j1+j2+j3+1));
  pre *= sqrt(hfact(j3+m3)*hfact(j3-m3)*hfact(j1-m1)*hfact(j1+m1)*hfact(j2-m2)*hfact(j2+m2));
  int k0 = 0; if (j2-j3-m1 > k0) k0 = j2-j3-m1; if (j1-j3+m2 > k0) k0 = j1-j3+m2;
  int k1 = j1+j2-j3; if (j1-m1 < k1) k1 = j1-m1; if (j2+m2 < k1) k1 = j2+m2;
  double s = 0.0;
  for (int k=k0;k<=k1;++k){
    double t = 1.0/(hfact(k)*hfact(j1+j2-j3-k)*hfact(j1-m1-k)*hfact(j2+m2-k)*hfact(j3-j2+m1+k)*hfact(j3-j1-m2+k));
    s += (k&1) ? -t : t;
  }
  return pre*s;
}

typedef std::complex<double> cd;

static void host_u(int l, cd U[5][5]){
  for (int a=0;a<5;++a) for (int b=0;b<5;++b) U[a][b] = 0.0;
  U[l][l] = 1.0;
  const double is2 = 1.0/sqrt(2.0);
  for (int m=1;m<=l;++m){
    double sgn = (m&1) ? -1.0 : 1.0;
    U[l+m][l+m] = sgn*is2;
    U[l+m][l-m] = is2;
    U[l-m][l-m] = cd(0.0, is2);
    U[l-m][l+m] = cd(0.0, -sgn*is2);
  }
}

static void host_real_cg(int l1,int l2,int l3, float* out){
  cd U1[5][5], U2[5][5], U3[5][5];
  host_u(l1,U1); host_u(l2,U2); host_u(l3,U3);
  int n1=2*l1+1, n2=2*l2+1, n3=2*l3+1;
  double cgt[5][5][5];
  for (int i=0;i<5;++i) for (int j=0;j<5;++j) for (int k=0;k<5;++k) cgt[i][j][k]=0.0;
  for (int m1=-l1;m1<=l1;++m1) for (int m2=-l2;m2<=l2;++m2){
    int m3 = m1+m2;
    if (m3 >= -l3 && m3 <= l3) cgt[l1+m1][l2+m2][l3+m3] = host_cgc(l1,m1,l2,m2,l3,m3);
  }
  cd W[5][5][5];
  double sre=0.0, sim=0.0;
  for (int c=0;c<n3;++c) for (int a=0;a<n1;++a) for (int b=0;b<n2;++b){
    cd acc = 0.0;
    for (int i=0;i<n1;++i) for (int j=0;j<n2;++j) for (int k=0;k<n3;++k)
      acc += U1[a][i]*U2[b][j]*std::conj(U3[c][k])*cgt[i][j][k];
    W[c][a][b] = acc;
    sre += fabs(acc.real()); sim += fabs(acc.imag());
  }
  bool use_re = (sre >= sim);
  for (int c=0;c<n3;++c) for (int a=0;a<n1;++a) for (int b=0;b<n2;++b)
    out[(c*n1+a)*n2+b] = (float)(use_re ? W[c][a][b].real() : W[c][a][b].imag());
}

static void build_cg_tables(CGTables& t){
  float w000[1];  host_real_cg(0,0,0,w000); t.c000 = w000[0];
  float w011[9];  host_real_cg(0,1,1,w011);
  for (int o=0;o<3;++o) for (int b=0;b<3;++b) t.c011[o][b] = w011[o*3+b];
  float w101[9];  host_real_cg(1,0,1,w101);
  for (int o=0;o<3;++o) for (int a=0;a<3;++a) t.c101[o][a] = w101[o*3+a];
  float w110[9];  host_real_cg(1,1,0,w110);
  for (int a=0;a<3;++a) for (int b=0;b<3;++b) t.c110[a][b] = w110[a*3+b];
  float w111[27]; host_real_cg(1,1,1,w111);
  for (int o=0;o<3;++o) for (int a=0;a<3;++a) for (int b=0;b<3;++b) t.c111[o][a][b] = w111[(o*3+a)*3+b];
  float w121[45]; host_real_cg(1,2,1,w121);
  for (int o=0;o<3;++o) for (int a=0;a<3;++a) for (int b=0;b<5;++b) t.c121[o][a][b] = w121[(o*3+a)*5+b];
}

// ---------------- device helpers ----------------
__device__ __forceinline__ float sspf(float v){
  float sp = (v > 30.0f) ? v : log1pf(expf(v));
  return sp - 0.69314718055994531f;
}

__device__ __forceinline__ float cutoff_w(float len){
  float u = len * (1.0f/1.5f);
  float u2 = u*u, u6 = u2*u2*u2, u7 = u6*u, u8 = u7*u;
  float cut = 1.0f - 28.0f*u6 + 48.0f*u7 - 21.0f*u8;
  return (u < 1.0f) ? cut : 0.0f;
}

// ================= CSR build =================
__global__ __launch_bounds__(256) void hist_kernel(const int* __restrict__ dst, int* __restrict__ hist){
  int e = blockIdx.x*256 + threadIdx.x;
  if (e >= NE) return;
  atomicAdd(&hist[dst[e]], 1);
}

__global__ __launch_bounds__(256) void scan1_kernel(const int* __restrict__ hist, int* __restrict__ bsum){
  __shared__ int s[256];
  int i = blockIdx.x*256 + threadIdx.x;
  int t = threadIdx.x;
  s[t] = (i < NN) ? hist[i] : 0;
  __syncthreads();
  for (int off=128; off>0; off>>=1){ if (t < off) s[t] += s[t+off]; __syncthreads(); }
  if (t == 0) bsum[blockIdx.x] = s[0];
}

__global__ __launch_bounds__(512) void scan2_kernel(const int* __restrict__ bsum, int* __restrict__ boff){
  __shared__ int s[512];
  int t = threadIdx.x;
  int v = (t < NBLK_SCAN) ? bsum[t] : 0;
  s[t] = v; __syncthreads();
  for (int off=1; off<512; off<<=1){
    int u = (t >= off) ? s[t-off] : 0;
    __syncthreads();
    s[t] += u;
    __syncthreads();
  }
  if (t < NBLK_SCAN) boff[t] = s[t] - v;
}

__global__ __launch_bounds__(256) void scan3_kernel(const int* __restrict__ hist, const int* __restrict__ boff,
                                                   int* __restrict__ rowptr, int* __restrict__ cursor){
  __shared__ int s[256];
  int i = blockIdx.x*256 + threadIdx.x;
  int t = threadIdx.x;
  int v = (i < NN) ? hist[i] : 0;
  s[t] = v; __syncthreads();
  for (int off=1; off<256; off<<=1){
    int u = (t >= off) ? s[t-off] : 0;
    __syncthreads();
    s[t] += u;
    __syncthreads();
  }
  int excl = s[t] - v + boff[blockIdx.x];
  if (i < NN){ rowptr[i] = excl; cursor[i] = excl; }
  if (i == 0) rowptr[NN] = NE;
}

__global__ __launch_bounds__(256) void scatter_kernel(const int* __restrict__ src, const int* __restrict__ dst,
    const float* __restrict__ sh, const float* __restrict__ elen, int* __restrict__ cursor,
    int* __restrict__ s_src, float* __restrict__ s_len, float* __restrict__ s_sh){
  int e = blockIdx.x*256 + threadIdx.x;
  if (e >= NE) return;
  int d = dst[e];
  int slot = atomicAdd(&cursor[d], 1);
  s_src[slot] = src[e];
  s_len[slot] = elen[e];
  const float* r = sh + (size_t)e*9;
  float* w = s_sh + (size_t)slot*9;
  #pragma unroll
  for (int k=0;k<9;++k) w[k] = r[k];
}

// ================= gather layers 1 & 2 (fused msg-agg + self-interaction + norm-act) =================
template<int LAYER>
__global__ __launch_bounds__(256) void gather12_kernel(
    const float* __restrict__ hin,
    const int* __restrict__ rowptr, const int* __restrict__ s_src,
    const float* __restrict__ s_len, const float* __restrict__ s_sh,
    const float* __restrict__ wpw, const float* __restrict__ wpb,
    const float* __restrict__ si, float* __restrict__ out, CGTables cg)
{
  constexpr int NPATH = (LAYER==2) ? 6 : 2;
  constexpr int NW = NPATH*80;            // 10 * NPATH*8
  __shared__ float sw[NW + NPATH*8];
  __shared__ float ssi[128];
  __shared__ float yx[32][33];
  for (int i=threadIdx.x;i<NW+NPATH*8;i+=256) sw[i] = (i<NW) ? wpw[i] : wpb[i-NW];
  if (threadIdx.x < 128) ssi[threadIdx.x] = si[threadIdx.x];
  __syncthreads();
  int gid = blockIdx.x*256 + threadIdx.x;   // grid exact: NN*8 threads
  int n = gid >> 3, c = gid & 7;
  int nl = threadIdx.x >> 3;
  int r0 = rowptr[n], r1 = rowptr[n+1];
  float a0=0.f, a1=0.f, a2=0.f, a3=0.f;
  for (int s=r0; s<r1; ++s){
    float len = s_len[s];
    int sn = s_src[s];
    const float* shr = s_sh + (size_t)s*9;
    float sh0 = shr[0], shx = shr[1], shy = shr[2], shz = shr[3];
    float emb[10];
    #pragma unroll
    for (int i=0;i<10;++i){
      float dd = len - (0.7f + (float)i*(1.0f/9.0f));
      emb[i] = __expf(-50.0f*dd*dd);
    }
    float w = cutoff_w(len);
    float lw[NPATH];
    #pragma unroll
    for (int p=0;p<NPATH;++p){
      float v = sw[NW + p*8 + c];
      #pragma unroll
      for (int i=0;i<10;++i) v += emb[i]*sw[i*(NPATH*8) + p*8 + c];
      lw[p] = v;
    }
    if constexpr (LAYER == 1){
      float x0 = hin[sn];
      a0 += cg.c000*sh0*x0*lw[0]*w;
      #pragma unroll
      for (int o=0;o<3;++o){
        float s011 = cg.c011[o][0]*shx + cg.c011[o][1]*shy + cg.c011[o][2]*shz;
        float v = s011*x0*lw[1]*w;
        if (o==0) a1 += v; else if (o==1) a2 += v; else a3 += v;
      }
    } else {
      float sh4 = shr[4], sh5 = shr[5], sh6 = shr[6], sh7 = shr[7], sh8 = shr[8];
      const float* hb = hin + (size_t)sn*32 + c;
      float x0 = hb[0], x1 = hb[8], x2 = hb[16], x3 = hb[24];
      float k110 = (cg.c110[0][0]*shx + cg.c110[0][1]*shy + cg.c110[0][2]*shz)*x1
                 + (cg.c110[1][0]*shx + cg.c110[1][1]*shy + cg.c110[1][2]*shz)*x2
                 + (cg.c110[2][0]*shx + cg.c110[2][1]*shy + cg.c110[2][2]*shz)*x3;
      a0 += (cg.c000*sh0*x0*lw[0] + k110*lw[3]) * w;
      #pragma unroll
      for (int o=0;o<3;++o){
        float s011 = cg.c011[o][0]*shx + cg.c011[o][1]*shy + cg.c011[o][2]*shz;
        float k101 = cg.c101[o][0]*x1 + cg.c101[o][1]*x2 + cg.c101[o][2]*x3;
        float k111 = (cg.c111[o][0][0]*shx + cg.c111[o][0][1]*shy + cg.c111[o][0][2]*shz)*x1
                   + (cg.c111[o][1][0]*shx + cg.c111[o][1][1]*shy + cg.c111[o][1][2]*shz)*x2
                   + (cg.c111[o][2][0]*shx + cg.c111[o][2][1]*shy + cg.c111[o][2][2]*shz)*x3;
        float k121 = (cg.c121[o][0][0]*sh4 + cg.c121[o][0][1]*sh5 + cg.c121[o][0][2]*sh6 + cg.c121[o][0][3]*sh7 + cg.c121[o][0][4]*sh8)*x1
                   + (cg.c121[o][1][0]*sh4 + cg.c121[o][1][1]*sh5 + cg.c121[o][1][2]*sh6 + cg.c121[o][1][3]*sh7 + cg.c121[o][1][4]*sh8)*x2
                   + (cg.c121[o][2][0]*sh4 + cg.c121[o][2][1]*sh5 + cg.c121[o][2][2]*sh6 + cg.c121[o][2][3]*sh7 + cg.c121[o][2][4]*sh8)*x3;
        float r = s011*x0*lw[1] + k101*sh0*lw[2] + k111*lw[4] + k121*lw[5];
        float v = r*w;
        if (o==0) a1 += v; else if (o==1) a2 += v; else a3 += v;
      }
    }
  }
  yx[nl][c] = a0; yx[nl][8+c] = a1; yx[nl][16+c] = a2; yx[nl][24+c] = a3;
  __syncthreads();
  float z0=0.f, z1=0.f, z2=0.f, z3=0.f;
  #pragma unroll
  for (int cc=0;cc<8;++cc){
    float w0 = ssi[cc*8+c], w1 = ssi[64+cc*8+c];
    z0 += yx[nl][cc]*w0;
    z1 += yx[nl][8+cc]*w1;
    z2 += yx[nl][16+cc]*w1;
    z3 += yx[nl][24+cc]*w1;
  }
  float n0 = sqrtf(z0*z0 + 1e-12f);
  float r0v = z0*(sspf(n0)/n0);
  float n1 = sqrtf(z1*z1 + z2*z2 + z3*z3 + 1e-12f);
  float sc = sspf(n1)/n1;
  float* orow = out + (size_t)n*32;
  orow[c] = r0v; orow[8+c] = z1*sc; orow[16+c] = z2*sc; orow[24+c] = z3*sc;
}

// ================= gather layer 3 (msg-agg + si3 + silu + graph pool) =================
__global__ __launch_bounds__(256) void gather3_kernel(
    const float* __restrict__ hin, const int* __restrict__ rowptr,
    const int* __restrict__ s_src, const float* __restrict__ s_len,
    const float* __restrict__ s_sh, const float* __restrict__ wpw,
    const float* __restrict__ wpb, const float* __restrict__ si,
    const int* __restrict__ batch, float* __restrict__ G, CGTables cg)
{
  __shared__ float sw[176];
  __shared__ float ssi[64];
  __shared__ float yx[32][9];
  __shared__ float lg[512];
  for (int i=threadIdx.x;i<176;i+=256) sw[i] = (i<160) ? wpw[i] : wpb[i-160];
  if (threadIdx.x < 64) ssi[threadIdx.x] = si[threadIdx.x];
  lg[threadIdx.x] = 0.f; lg[256+threadIdx.x] = 0.f;
  __syncthreads();
  int gid = blockIdx.x*256 + threadIdx.x;
  int n = gid >> 3, c = gid & 7;
  int nl = threadIdx.x >> 3;
  int r0 = rowptr[n], r1 = rowptr[n+1];
  float acc = 0.f;
  for (int s=r0; s<r1; ++s){
    float len = s_len[s];
    int sn = s_src[s];
    const float* shr = s_sh + (size_t)s*9;
    float sh0 = shr[0], shx = shr[1], shy = shr[2], shz = shr[3];
    float emb[10];
    #pragma unroll
    for (int i=0;i<10;++i){
      float dd = len - (0.7f + (float)i*(1.0f/9.0f));
      emb[i] = __expf(-50.0f*dd*dd);
    }
    float w = cutoff_w(len);
    float lw0 = sw[160 + c], lw1 = sw[160 + 8 + c];
    #pragma unroll
    for (int i=0;i<10;++i){
      lw0 += emb[i]*sw[i*16 + c];
      lw1 += emb[i]*sw[i*16 + 8 + c];
    }
    const float* hb = hin + (size_t)sn*32 + c;
    float x0 = hb[0], x1 = hb[8], x2 = hb[16], x3 = hb[24];
    float k110 = (cg.c110[0][0]*shx + cg.c110[0][1]*shy + cg.c110[0][2]*shz)*x1
               + (cg.c110[1][0]*shx + cg.c110[1][1]*shy + cg.c110[1][2]*shz)*x2
               + (cg.c110[2][0]*shx + cg.c110[2][1]*shy + cg.c110[2][2]*shz)*x3;
    acc += (cg.c000*sh0*x0*lw0 + k110*lw1) * w;
  }
  yx[nl][c] = acc;
  __syncthreads();
  float z = 0.f;
  #pragma unroll
  for (int cc=0;cc<8;++cc) z += yx[nl][cc]*ssi[cc*8+c];
  float v = z / (1.0f + expf(-z));
  atomicAdd(&lg[batch[n]*8 + c], v);
  __syncthreads();
  int t = threadIdx.x;
  float v0 = lg[t];     if (v0 != 0.f) unsafeAtomicAdd(&G[t], v0);
  float v1 = lg[256+t]; if (v1 != 0.f) unsafeAtomicAdd(&G[256+t], v1);
}

// ================= final: logits + softmax =================
__global__ void final_kernel(
    const float* __restrict__ g, const float* __restrict__ ow,
    const float* __restrict__ ob, float* __restrict__ out)
{
  int i = threadIdx.x;
  if (i >= NG) return;
  float gv[8];
  #pragma unroll
  for (int c=0;c<8;++c) gv[c] = g[i*8+c];
  float lg[8];
  #pragma unroll
  for (int j=0;j<8;++j){
    float acc = ob[j];
    #pragma unroll
    for (int c=0;c<8;++c) acc += gv[c]*ow[c*8+j];
    lg[j] = acc;
  }
  float mx = lg[0];
  #pragma unroll
  for (int j=1;j<8;++j) mx = fmaxf(mx, lg[j]);
  float ssum = 0.0f;
  #pragma unroll
  for (int j=0;j<8;++j){ lg[j] = expf(lg[j]-mx); ssum += lg[j]; }
  float inv = 1.0f/ssum;
  #pragma unroll
  for (int j=0;j<8;++j) out[i*8+j] = lg[j]*inv;
}

// ================= FALLBACK (round-1 atomic path) =================
__global__ __launch_bounds__(256) void edge1_kernel(
    const float* __restrict__ x, const int* __restrict__ src, const int* __restrict__ dst,
    const float* __restrict__ sh, const float* __restrict__ elen,
    const float* __restrict__ wpw, const float* __restrict__ wpb,
    float* __restrict__ agg, CGTables cg)
{
  __shared__ float sw[176];
  for (int i=threadIdx.x;i<176;i+=256) sw[i] = (i<160) ? wpw[i] : wpb[i-160];
  __syncthreads();
  int e = blockIdx.x*256 + threadIdx.x;
  if (e >= NE) return;
  float len = elen[e];
  float lw[16];
  #pragma unroll
  for (int j=0;j<16;++j) lw[j] = sw[160+j];
  #pragma unroll
  for (int i=0;i<10;++i){
    float dd = len - (0.7f + (float)i*(1.0f/9.0f));
    float em = __expf(-50.0f*dd*dd);
    #pragma unroll
    for (int j=0;j<16;++j) lw[j] += em*sw[i*16+j];
  }
  float w = cutoff_w(len);
  int s = src[e], d = dst[e];
  float x0 = x[s];
  const float* shr = sh + (size_t)e*9;
  float sh0 = shr[0], sh1 = shr[1], sh2 = shr[2], sh3 = shr[3];
  float* ag = agg + (size_t)d*32;
  float b0 = cg.c000*x0*sh0*w;
  #pragma unroll
  for (int j=0;j<8;++j) unsafeAtomicAdd(ag+j, b0*lw[j]);
  #pragma unroll
  for (int o=0;o<3;++o){
    float s011 = cg.c011[o][0]*sh1 + cg.c011[o][1]*sh2 + cg.c011[o][2]*sh3;
    float bo = s011*x0*w;
    #pragma unroll
    for (int j=0;j<8;++j) unsafeAtomicAdd(ag+(1+o)*8+j, bo*lw[8+j]);
  }
}

__global__ __launch_bounds__(256) void edge2_kernel(
    const float* __restrict__ h, const int* __restrict__ src, const int* __restrict__ dst,
    const float* __restrict__ sh, const float* __restrict__ elen,
    const float* __restrict__ wpw, const float* __restrict__ wpb,
    float* __restrict__ agg, CGTables cg)
{
  __shared__ float sw[528];
  for (int i=threadIdx.x;i<528;i+=256) sw[i] = (i<480) ? wpw[i] : wpb[i-480];
  __syncthreads();
  int e = blockIdx.x*256 + threadIdx.x;
  if (e >= NE) return;
  float len = elen[e];
  float lw[48];
  #pragma unroll
  for (int j=0;j<48;++j) lw[j] = sw[480+j];
  #pragma unroll
  for (int i=0;i<10;++i){
    float dd = len - (0.7f + (float)i*(1.0f/9.0f));
    float em = __expf(-50.0f*dd*dd);
    #pragma unroll
    for (int j=0;j<48;++j) lw[j] += em*sw[i*48+j];
  }
  float w = cutoff_w(len);
  int s = src[e], d = dst[e];
  float shv[9];
  const float* shr = sh + (size_t)e*9;
  #pragma unroll
  for (int i=0;i<9;++i) shv[i] = shr[i];
  float sh0 = shv[0];
  float s011[3], k110[3], k111[3][3], k121[3][3];
  #pragma unroll
  for (int o=0;o<3;++o) s011[o] = cg.c011[o][0]*shv[1] + cg.c011[o][1]*shv[2] + cg.c011[o][2]*shv[3];
  #pragma unroll
  for (int a=0;a<3;++a) k110[a] = cg.c110[a][0]*shv[1] + cg.c110[a][1]*shv[2] + cg.c110[a][2]*shv[3];
  #pragma unroll
  for (int o=0;o<3;++o)
    #pragma unroll
    for (int a=0;a<3;++a)
      k111[o][a] = cg.c111[o][a][0]*shv[1] + cg.c111[o][a][1]*shv[2] + cg.c111[o][a][2]*shv[3];
  #pragma unroll
  for (int o=0;o<3;++o)
    #pragma unroll
    for (int a=0;a<3;++a){
      float acc = 0.0f;
      #pragma unroll
      for (int b=0;b<5;++b) acc += cg.c121[o][a][b]*shv[4+b];
      k121[o][a] = acc;
    }
  const float4* hr = reinterpret_cast<const float4*>(h + (size_t)s*32);
  float xs[32];
  #pragma unroll
  for (int i=0;i<8;++i){
    float4 q = hr[i];
    xs[i*4] = q.x; xs[i*4+1] = q.y; xs[i*4+2] = q.z; xs[i*4+3] = q.w;
  }
  float* ag = agg + (size_t)d*32;
  #pragma unroll
  for (int c=0;c<8;++c){
    float x0 = xs[c], x1 = xs[8+c], x2 = xs[16+c], x3 = xs[24+c];
    float r0 = cg.c000*sh0*x0*lw[c]
             + (k110[0]*x1 + k110[1]*x2 + k110[2]*x3)*lw[24+c];
    unsafeAtomicAdd(ag+c, r0*w);
    #pragma unroll
    for (int o=0;o<3;++o){
      float r = s011[o]*x0*lw[8+c]
              + (cg.c101[o][0]*x1 + cg.c101[o][1]*x2 + cg.c101[o][2]*x3)*sh0*lw[16+c]
              + (k111[o][0]*x1 + k111[o][1]*x2 + k111[o][2]*x3)*lw[32+c]
              + (k121[o][0]*x1 + k121[o][1]*x2 + k121[o][2]*x3)*lw[40+c];
      unsafeAtomicAdd(ag+(1+o)*8+c, r*w);
    }
  }
}

__global__ __launch_bounds__(256) void edge3_kernel(
    const float* __restrict__ h, const int* __restrict__ src, const int* __restrict__ dst,
    const float* __restrict__ sh, const float* __restrict__ elen,
    const float* __restrict__ wpw, const float* __restrict__ wpb,
    float* __restrict__ agg, CGTables cg)
{
  __shared__ float sw[176];
  for (int i=threadIdx.x;i<176;i+=256) sw[i] = (i<160) ? wpw[i] : wpb[i-160];
  __syncthreads();
  int e = blockIdx.x*256 + threadIdx.x;
  if (e >= NE) return;
  float len = elen[e];
  float lw[16];
  #pragma unroll
  for (int j=0;j<16;++j) lw[j] = sw[160+j];
  #pragma unroll
  for (int i=0;i<10;++i){
    float dd = len - (0.7f + (float)i*(1.0f/9.0f));
    float em = __expf(-50.0f*dd*dd);
    #pragma unroll
    for (int j=0;j<16;++j) lw[j] += em*sw[i*16+j];
  }
  float w = cutoff_w(len);
  int s = src[e], d = dst[e];
  const float* shr = sh + (size_t)e*9;
  float sh0 = shr[0], sh1 = shr[1], sh2 = shr[2], sh3 = shr[3];
  float k110[3];
  #pragma unroll
  for (int a=0;a<3;++a) k110[a] = cg.c110[a][0]*sh1 + cg.c110[a][1]*sh2 + cg.c110[a][2]*sh3;
  const float4* hr = reinterpret_cast<const float4*>(h + (size_t)s*32);
  float xs[32];
  #pragma unroll
  for (int i=0;i<8;++i){
    float4 q = hr[i];
    xs[i*4] = q.x; xs[i*4+1] = q.y; xs[i*4+2] = q.z; xs[i*4+3] = q.w;
  }
  float* ag = agg + (size_t)d*8;
  #pragma unroll
  for (int c=0;c<8;++c){
    float r = cg.c000*sh0*xs[c]*lw[c]
            + (k110[0]*xs[8+c] + k110[1]*xs[16+c] + k110[2]*xs[24+c])*lw[8+c];
    unsafeAtomicAdd(ag+c, r*w);
  }
}

__global__ __launch_bounds__(256) void node_kernel(
    const float* __restrict__ agg, const float* __restrict__ si,
    float* __restrict__ out)
{
  __shared__ float s_si[128];
  if (threadIdx.x < 128) s_si[threadIdx.x] = si[threadIdx.x];
  __syncthreads();
  int idx = blockIdx.x*256 + threadIdx.x;
  if (idx >= NN*8) return;
  int n = idx >> 3, d = idx & 7;
  const float* ar = agg + (size_t)n*32;
  float y[4];
  #pragma unroll
  for (int m=0;m<4;++m){
    const float* sm = s_si + (m ? 64 : 0);
    float acc = 0.0f;
    #pragma unroll
    for (int c=0;c<8;++c) acc += ar[m*8+c]*sm[c*8+d];
    y[m] = acc;
  }
  float n0 = sqrtf(y[0]*y[0] + 1e-12f);
  float r0 = y[0]*(sspf(n0)/n0);
  float n1 = sqrtf(y[1]*y[1] + y[2]*y[2] + y[3]*y[3] + 1e-12f);
  float sc = sspf(n1)/n1;
  float* orow = out + (size_t)n*32;
  orow[d]      = r0;
  orow[8+d]    = y[1]*sc;
  orow[16+d]   = y[2]*sc;
  orow[24+d]   = y[3]*sc;
}

__global__ __launch_bounds__(256) void node3_pool_kernel(
    const float* __restrict__ agg, const float* __restrict__ si,
    const int* __restrict__ batch, float* __restrict__ g)
{
  __shared__ float s_si[64];
  if (threadIdx.x < 64) s_si[threadIdx.x] = si[threadIdx.x];
  __syncthreads();
  int n = blockIdx.x*256 + threadIdx.x;
  if (n >= NN) return;
  const float* ar = agg + (size_t)n*8;
  float av[8];
  #pragma unroll
  for (int c=0;c<8;++c) av[c] = ar[c];
  int b = batch[n];
  float* gr = g + (size_t)b*8;
  #pragma unroll
  for (int d=0;d<8;++d){
    float acc = 0.0f;
    #pragma unroll
    for (int c=0;c<8;++c) acc += av[c]*s_si[c*8+d];
    float v = acc / (1.0f + expf(-acc));
    unsafeAtomicAdd(gr+d, v);
  }
}

// ================= launch =================
extern "C" void kernel_launch(void* const* d_in, const int* in_sizes, int n_in,
                              void* d_out, int out_size, void* d_ws, size_t ws_size,
                              hipStream_t stream)
{
  const float* x     = (const float*)d_in[0];
  const int*   eidx  = (const int*)  d_in[1];
  const float* esh   = (const float*)d_in[2];
  const float* elen  = (const float*)d_in[3];
  const int*   batch = (const int*)  d_in[4];
  const float* wp1w  = (const float*)d_in[5];
  const float* wp1b  = (const float*)d_in[6];
  const float* wp2w  = (const float*)d_in[7];
  const float* wp2b  = (const float*)d_in[8];
  const float* wp3w  = (const float*)d_in[9];
  const float* wp3b  = (const float*)d_in[10];
  const float* si1   = (const float*)d_in[11];
  const float* si2   = (const float*)d_in[12];
  const float* si3   = (const float*)d_in[13];
  const float* outw  = (const float*)d_in[14];
  const float* outb  = (const float*)d_in[15];
  const int* src = eidx;
  const int* dst = eidx + NE;

  CGTables cg;
  build_cg_tables(cg);

  // ---- CSR-gather layout ----
  char* p = (char*)d_ws;
  auto carve = [&](size_t elems) -> void* {
    void* r = (void*)p;
    p += ((elems*4 + 255)/256)*256;
    return r;
  };
  int*   rowptr = (int*)  carve(NN+1);
  int*   cursor = (int*)  carve(NN);
  int*   hist   = (int*)  carve(NN);
  int*   bsum   = (int*)  carve(512);
  int*   boff   = (int*)  carve(512);
  int*   ssrc   = (int*)  carve(NE);
  float* slen   = (float*)carve(NE);
  float* ssh    = (float*)carve((size_t)NE*9);
  float* B1     = (float*)carve((size_t)NN*32);
  float* B2     = (float*)carve((size_t)NN*32);
  float* G      = (float*)carve(512);
  size_t need = (size_t)(p - (char*)d_ws);

  if (ws_size >= need){
    hipMemsetAsync(hist, 0, NN*sizeof(int), stream);
    hipMemsetAsync(G, 0, 512*sizeof(float), stream);
    hist_kernel<<<NBLK_E, 256, 0, stream>>>(dst, hist);
    scan1_kernel<<<NBLK_SCAN, 256, 0, stream>>>(hist, bsum);
    scan2_kernel<<<1, 512, 0, stream>>>(bsum, boff);
    scan3_kernel<<<NBLK_SCAN, 256, 0, stream>>>(hist, boff, rowptr, cursor);
    scatter_kernel<<<NBLK_E, 256, 0, stream>>>(src, dst, esh, elen, cursor, ssrc, slen, ssh);
    gather12_kernel<1><<<NBLK_N8, 256, 0, stream>>>(x,  rowptr, ssrc, slen, ssh, wp1w, wp1b, si1, B1, cg);
    gather12_kernel<2><<<NBLK_N8, 256, 0, stream>>>(B1, rowptr, ssrc, slen, ssh, wp2w, wp2b, si2, B2, cg);
    gather3_kernel<<<NBLK_N8, 256, 0, stream>>>(B2, rowptr, ssrc, slen, ssh, wp3w, wp3b, si3, batch, G, cg);
    final_kernel<<<1, 64, 0, stream>>>(G, outw, outb, (float*)d_out);
  } else {
    // fallback: atomic-scatter path (round-1), needs ~29 MB
    float* A  = (float*)d_ws;
    float* Bf = A + (size_t)NN*32;
    float* Cf = Bf + (size_t)NN*32;
    float* Gf = Cf + (size_t)NN*8;
    const int EB = NBLK_E, NB8 = NBLK_N8, NB = (NN + 255)/256;
    hipMemsetAsync(A, 0, (size_t)NN*32*sizeof(float), stream);
    edge1_kernel<<<EB, 256, 0, stream>>>(x, src, dst, esh, elen, wp1w, wp1b, A, cg);
    node_kernel<<<NB8, 256, 0, stream>>>(A, si1, Bf);
    hipMemsetAsync(A, 0, (size_t)NN*32*sizeof(float), stream);
    edge2_kernel<<<EB, 256, 0, stream>>>(Bf, src, dst, esh, elen, wp2w, wp2b, A, cg);
    node_kernel<<<NB8, 256, 0, stream>>>(A, si2, Bf);
    hipMemsetAsync(Cf, 0, (size_t)NN*8*sizeof(float), stream);
    edge3_kernel<<<EB, 256, 0, stream>>>(Bf, src, dst, esh, elen, wp3w, wp3b, Cf, cg);
    hipMemsetAsync(Gf, 0, (size_t)NG*8*sizeof(float), stream);
    node3_pool_kernel<<<NB, 256, 0, stream>>>(Cf, si3, batch, Gf);
    final_kernel<<<1, 64, 0, stream>>>(Gf, outw, outb, (float*)d_out);
  }
}